// Round 5
// baseline (629.771 us; speedup 1.0000x reference)
//
#include <hip/hip_runtime.h>

constexpr int NN = 50000;     // nodes
constexpr int NE = 800000;    // edges
constexpr float SLOPE_A = 0.2f;   // attention leaky_relu
constexpr float SLOPE_R = 0.01f;  // activation leaky_relu
constexpr int SCB = 196;      // scan blocks: 196*256 = 50176 >= NN

typedef __attribute__((ext_vector_type(8))) short bf16x8;
typedef __attribute__((ext_vector_type(4))) float f32x4;

__device__ __forceinline__ unsigned short f2bf(float f) {
    union { float f; unsigned u; } v; v.f = f;
    unsigned u = v.u;
    unsigned r = u + 0x7fffu + ((u >> 16) & 1u);  // round-to-nearest-even
    return (unsigned short)(r >> 16);
}
__device__ __forceinline__ float bf2f(unsigned short s) {
    union { unsigned u; float f; } v; v.u = ((unsigned)s) << 16;
    return v.f;
}

// ---------------- CSR build ----------------
__global__ void k_hist(const int* __restrict__ dst, int* __restrict__ cnt) {
    int i = blockIdx.x * 256 + threadIdx.x;
    if (i < NE) atomicAdd(&cnt[dst[i]], 1);
}

__global__ void k_scan1(const int* __restrict__ cnt, int* __restrict__ loc,
                        int* __restrict__ bsum) {
    __shared__ int sh[256];
    int t = threadIdx.x;
    int i = blockIdx.x * 256 + t;
    int v = (i < NN) ? cnt[i] : 0;
    sh[t] = v;
    __syncthreads();
    for (int off = 1; off < 256; off <<= 1) {
        int tmp = (t >= off) ? sh[t - off] : 0;
        __syncthreads();
        sh[t] += tmp;
        __syncthreads();
    }
    loc[i] = sh[t] - v;
    if (t == 255) bsum[blockIdx.x] = sh[255];
}

__global__ void k_scan2(const int* __restrict__ bsum, int* __restrict__ boff,
                        int* __restrict__ rowptr) {
    __shared__ int sh[256];
    int t = threadIdx.x;
    int v = (t < SCB) ? bsum[t] : 0;
    sh[t] = v;
    __syncthreads();
    for (int off = 1; off < 256; off <<= 1) {
        int tmp = (t >= off) ? sh[t - off] : 0;
        __syncthreads();
        sh[t] += tmp;
        __syncthreads();
    }
    if (t < SCB) boff[t] = sh[t] - v;
    if (t == 255) rowptr[NN] = sh[255];
}

__global__ void k_scan3(const int* __restrict__ loc, const int* __restrict__ boff,
                        int* __restrict__ rowptr, int* __restrict__ cursor) {
    int i = blockIdx.x * 256 + threadIdx.x;
    if (i < NN) {
        int r = loc[i] + boff[blockIdx.x];
        rowptr[i] = r;
        cursor[i] = r;
    }
}

__global__ void k_scatter(const int* __restrict__ src, const int* __restrict__ dst,
                          int* __restrict__ cursor, int* __restrict__ ssrc) {
    int i = blockIdx.x * 256 + threadIdx.x;
    if (i < NE) {
        int d = dst[i];
        int pos = atomicAdd(&cursor[d], 1);
        ssrc[pos] = src[i];
    }
}

// ---------------- W -> bf16 transposed (Wt[j][k] = W[k][j]) ----------------
__global__ void k_prepw(const float* __restrict__ W1, const float* __restrict__ W2,
                        const float* __restrict__ W3, unsigned short* __restrict__ Wt) {
    int b = blockIdx.x;          // 768 = 3 layers * 256 k-rows
    int L = b >> 8, k = b & 255;
    const float* W = (L == 0) ? W1 : ((L == 1) ? W2 : W3);
    int j = threadIdx.x;
    Wt[L * 65536 + j * 256 + k] = f2bf(W[k * 256 + j]);
}

// ---------------- x fp32 -> bf16 ----------------
__global__ void k_xcast(const float* __restrict__ x, unsigned short* __restrict__ xbf) {
    size_t i = (size_t)blockIdx.x * 256 + threadIdx.x;  // group of 4 elems
    float4 v = *(const float4*)(x + i * 4);
    ushort4 p;
    p.x = f2bf(v.x); p.y = f2bf(v.y); p.z = f2bf(v.z); p.w = f2bf(v.w);
    *(ushort4*)(xbf + i * 4) = p;
}

// ---------------- BN fold: Wt2[j][k] = sc[k]*Wt[j][k]; c[j] = sum_k sh[k]*Wt[j][k]
__global__ void k_fold(const unsigned short* __restrict__ Wsrc, const float* __restrict__ sc,
                       const float* __restrict__ sh, unsigned short* __restrict__ Wt2,
                       float* __restrict__ cvec) {
    __shared__ float red[256];
    int j = blockIdx.x, k = threadIdx.x;
    float w = bf2f(Wsrc[j * 256 + k]);
    float s = sc ? sc[k] : 1.f;
    float hs = sh ? sh[k] : 0.f;
    Wt2[j * 256 + k] = f2bf(s * w);
    red[k] = hs * w;
    __syncthreads();
    for (int off = 128; off > 0; off >>= 1) {
        if (k < off) red[k] += red[k + off];
        __syncthreads();
    }
    if (k == 0) cvec[j] = red[0];
}

// ---------------- GEMM: feat = A(bf16) @ Wt2 + c  (bf16 MFMA, fp32 acc) --------
// block: 256 thr = 4 waves; tile 64 rows x 256 cols; wave w owns cols [64w,64w+64)
// = head w. BN pre-folded into Wt2/c. A staged as raw bf16 16B copies.
// Fused epilogue: +c, el/er attention dots, bf16 feat store.
__launch_bounds__(256, 2)
__global__ void k_gemm(const unsigned short* __restrict__ A, const unsigned short* __restrict__ Wt,
                       const float* __restrict__ cvec,
                       const float* __restrict__ al, const float* __restrict__ ar,
                       unsigned short* __restrict__ feat16, float* __restrict__ el,
                       float* __restrict__ er) {
    constexpr int AP = 264;  // A lds pitch in bf16 elems (row start 16B-aligned)
    __shared__ __align__(16) unsigned short Alds[64 * AP];
    const int tid = threadIdx.x;
    const int rowbase = blockIdx.x * 64;

    // stage A: 64 rows x 256 bf16, pure 16B copies (32 chunks of 16B per row)
    for (int it = 0; it < 8; it++) {
        int idx = it * 256 + tid;       // 0..2047
        int rr = idx >> 5;              // row 0..63
        int c16 = idx & 31;             // 16B chunk
        int gr = rowbase + rr;
        uint4 v = make_uint4(0u, 0u, 0u, 0u);
        if (gr < NN) v = *(const uint4*)(A + (size_t)gr * 256 + c16 * 8);
        *(uint4*)(&Alds[rr * AP + c16 * 8]) = v;
    }
    __syncthreads();

    f32x4 acc[4][4];
    for (int i = 0; i < 4; i++)
        for (int j = 0; j < 4; j++)
            acc[i][j] = (f32x4){0.f, 0.f, 0.f, 0.f};

    const int lane = tid & 63, w = tid >> 6;
    const int mm = lane & 15, q = lane >> 4;

    const unsigned short* bbase = Wt + ((size_t)(64 * w + mm)) * 256 + q * 8;

#pragma unroll
    for (int kc = 0; kc < 8; kc++) {
        bf16x8 a[4], b[4];
        for (int i = 0; i < 4; i++)
            a[i] = *(const bf16x8*)(&Alds[(16 * i + mm) * AP + kc * 32 + q * 8]);
        for (int j = 0; j < 4; j++)
            b[j] = *(const bf16x8*)(bbase + j * (16 * 256) + kc * 32);
        for (int i = 0; i < 4; i++)
            for (int j = 0; j < 4; j++)
                acc[i][j] = __builtin_amdgcn_mfma_f32_16x16x32_bf16(a[i], b[j], acc[i][j], 0, 0, 0);
    }

    // ---- add folded-BN column offset c ----
    float cv[4];
    for (int j = 0; j < 4; j++) cv[j] = cvec[64 * w + 16 * j + mm];
    for (int i = 0; i < 4; i++)
        for (int j = 0; j < 4; j++)
            for (int r = 0; r < 4; r++)
                acc[i][j][r] += cv[j];

    // ---- fused el/er: head w cols are exactly this wave's 64 cols ----
    float alv[4], arv[4];
    for (int j = 0; j < 4; j++) {
        alv[j] = al[w * 64 + 16 * j + mm];
        arv[j] = ar[w * 64 + 16 * j + mm];
    }
    for (int i = 0; i < 4; i++) {
        for (int r = 0; r < 4; r++) {
            int gr = rowbase + 16 * i + q * 4 + r;
            float se = 0.f, sr = 0.f;
            for (int j = 0; j < 4; j++) {
                se += acc[i][j][r] * alv[j];
                sr += acc[i][j][r] * arv[j];
            }
            for (int off = 1; off < 16; off <<= 1) {
                se += __shfl_xor(se, off, 64);
                sr += __shfl_xor(sr, off, 64);
            }
            if (mm == 0 && gr < NN) {
                el[gr * 4 + w] = se;
                er[gr * 4 + w] = sr;
            }
        }
    }

    // ---- feat store as bf16 (C/D layout: col=lane&15, row=(lane>>4)*4+reg) ----
    for (int i = 0; i < 4; i++) {
        for (int j = 0; j < 4; j++) {
            int gc = 64 * w + 16 * j + mm;
            for (int r = 0; r < 4; r++) {
                int gr = rowbase + 16 * i + q * 4 + r;
                if (gr < NN) feat16[(size_t)gr * 256 + gc] = f2bf(acc[i][j][r]);
            }
        }
    }
}

// ---------------- per-dst softmax + weighted aggregation (bf16 gather) ----------------
// one wave per destination node; lane l owns channels [4l, 4l+4); head h = l>>4.
// No-max softmax (scores bounded). Predicated unroll-8, 8 gathers in flight.
// resid is bf16; out is bf16 hbuf (layers 1-2) or fp32 head-mean (final).
__launch_bounds__(256)
__global__ void k_agg(const unsigned short* __restrict__ feat16, const float* __restrict__ el,
                      const float* __restrict__ er, const int* __restrict__ rowptr,
                      const int* __restrict__ ssrc, const unsigned short* __restrict__ resid,
                      const float* __restrict__ bnscale, const float* __restrict__ bnshift,
                      int use_bn, const float* __restrict__ bias, int act,
                      unsigned short* __restrict__ outh, float* __restrict__ outf,
                      int final_mean) {
    int n = __builtin_amdgcn_readfirstlane(blockIdx.x * 4 + (threadIdx.x >> 6));
    int l = threadIdx.x & 63;
    int h = l >> 4;
    int beg = rowptr[n], end = rowptr[n + 1];
    float erh = er[n * 4 + h];

    float d = 0.f;
    float4 acc = make_float4(0.f, 0.f, 0.f, 0.f);

    for (int e = beg; e < end; e += 8) {
        int ss[8];
        float cc[8];
        ushort4 ff[8];
#pragma unroll
        for (int j = 0; j < 8; j++) {
            int ee = e + j;
            ss[j] = ssrc[(ee < end) ? ee : beg];
        }
#pragma unroll
        for (int j = 0; j < 8; j++)
            cc[j] = el[ss[j] * 4 + h];
#pragma unroll
        for (int j = 0; j < 8; j++)
            ff[j] = *(const ushort4*)(feat16 + (size_t)ss[j] * 256 + l * 4);
#pragma unroll
        for (int j = 0; j < 8; j++) {
            float sc = cc[j] + erh;
            sc = (sc > 0.f) ? sc : SLOPE_A * sc;
            float wgt = ((e + j) < end) ? __expf(sc) : 0.f;
            d += wgt;
            acc.x += bf2f(ff[j].x) * wgt;
            acc.y += bf2f(ff[j].y) * wgt;
            acc.z += bf2f(ff[j].z) * wgt;
            acc.w += bf2f(ff[j].w) * wgt;
        }
    }

    float invd = 1.f / fmaxf(d, 1e-9f);
    acc.x *= invd; acc.y *= invd; acc.z *= invd; acc.w *= invd;

    // residual (+BN) + bias
    ushort4 rv = *(const ushort4*)(resid + (size_t)n * 256 + l * 4);
    float4 r = make_float4(bf2f(rv.x), bf2f(rv.y), bf2f(rv.z), bf2f(rv.w));
    if (use_bn) {
        float4 sc4 = *(const float4*)(bnscale + l * 4);
        float4 sh4 = *(const float4*)(bnshift + l * 4);
        r.x = r.x * sc4.x + sh4.x;
        r.y = r.y * sc4.y + sh4.y;
        r.z = r.z * sc4.z + sh4.z;
        r.w = r.w * sc4.w + sh4.w;
    }
    float4 bb = *(const float4*)(bias + l * 4);
    acc.x += r.x + bb.x; acc.y += r.y + bb.y;
    acc.z += r.z + bb.z; acc.w += r.w + bb.w;
    if (act) {
        acc.x = (acc.x > 0.f) ? acc.x : SLOPE_R * acc.x;
        acc.y = (acc.y > 0.f) ? acc.y : SLOPE_R * acc.y;
        acc.z = (acc.z > 0.f) ? acc.z : SLOPE_R * acc.z;
        acc.w = (acc.w > 0.f) ? acc.w : SLOPE_R * acc.w;
    }

    if (!final_mean) {
        ushort4 p;
        p.x = f2bf(acc.x); p.y = f2bf(acc.y); p.z = f2bf(acc.z); p.w = f2bf(acc.w);
        *(ushort4*)(outh + (size_t)n * 256 + l * 4) = p;
    } else {
        acc.x += __shfl_xor(acc.x, 16, 64); acc.x += __shfl_xor(acc.x, 32, 64);
        acc.y += __shfl_xor(acc.y, 16, 64); acc.y += __shfl_xor(acc.y, 32, 64);
        acc.z += __shfl_xor(acc.z, 16, 64); acc.z += __shfl_xor(acc.z, 32, 64);
        acc.w += __shfl_xor(acc.w, 16, 64); acc.w += __shfl_xor(acc.w, 32, 64);
        if (l < 16) {
            acc.x *= 0.25f; acc.y *= 0.25f; acc.z *= 0.25f; acc.w *= 0.25f;
            *(float4*)(outf + (size_t)n * 64 + l * 4) = acc;
        }
    }
}

// ---------------- BatchNorm stats (bf16 input) ----------------
__global__ void k_bnstats(const unsigned short* __restrict__ hh, float* __restrict__ sums) {
    int t = threadIdx.x;
    int b = blockIdx.x;
    int r0 = b * 196, r1 = min(r0 + 196, NN);
    float s = 0.f, s2 = 0.f;
    for (int r = r0; r < r1; r++) {
        float v = bf2f(hh[(size_t)r * 256 + t]);
        s += v; s2 += v * v;
    }
    atomicAdd(&sums[t], s);
    atomicAdd(&sums[256 + t], s2);
}

__global__ void k_bnfinal(const float* __restrict__ sums, const float* __restrict__ g,
                          const float* __restrict__ be, float* __restrict__ scale,
                          float* __restrict__ shift) {
    int t = threadIdx.x;
    float mu = sums[t] * (1.f / NN);
    float var = sums[256 + t] * (1.f / NN) - mu * mu;
    float rs = rsqrtf(var + 1e-5f);
    float sc = rs * g[t];
    scale[t] = sc;
    shift[t] = be[t] - mu * sc;
}

// ---------------- launcher ----------------
extern "C" void kernel_launch(void* const* d_in, const int* in_sizes, int n_in,
                              void* d_out, int out_size, void* d_ws, size_t ws_size,
                              hipStream_t stream) {
    const float* x   = (const float*)d_in[0];
    const int* src   = (const int*)d_in[1];
    const int* dst   = (const int*)d_in[2];
    const float* W1  = (const float*)d_in[3];
    const float* al1 = (const float*)d_in[4];
    const float* ar1 = (const float*)d_in[5];
    const float* b1  = (const float*)d_in[6];
    const float* W2  = (const float*)d_in[7];
    const float* al2 = (const float*)d_in[8];
    const float* ar2 = (const float*)d_in[9];
    const float* b2  = (const float*)d_in[10];
    const float* W3  = (const float*)d_in[11];
    const float* al3 = (const float*)d_in[12];
    const float* ar3 = (const float*)d_in[13];
    const float* b3  = (const float*)d_in[14];
    const float* g1  = (const float*)d_in[15];
    const float* be1 = (const float*)d_in[16];
    const float* g2  = (const float*)d_in[17];
    const float* be2 = (const float*)d_in[18];
    float* out = (float*)d_out;

    char* ws = (char*)d_ws;
    size_t off = 0;
    auto alloc = [&](size_t bytes) {
        void* p = ws + off;
        off += (bytes + 255) & ~(size_t)255;
        return p;
    };
    int* rowptr = (int*)alloc((NN + 1) * sizeof(int));
    int* cursor = (int*)alloc(NN * sizeof(int));
    int* cnt    = (int*)alloc(SCB * 256 * sizeof(int));
    int* loc    = (int*)alloc(SCB * 256 * sizeof(int));
    int* bsum   = (int*)alloc(SCB * sizeof(int));
    int* boff   = (int*)alloc(SCB * sizeof(int));
    int* ssrc   = (int*)alloc(NE * sizeof(int));
    unsigned short* xbf    = (unsigned short*)alloc((size_t)NN * 256 * sizeof(unsigned short));
    unsigned short* feat16 = (unsigned short*)alloc((size_t)NN * 256 * sizeof(unsigned short));
    unsigned short* hbuf   = (unsigned short*)alloc((size_t)NN * 256 * sizeof(unsigned short));
    float* el   = (float*)alloc((size_t)NN * 4 * sizeof(float));
    float* er   = (float*)alloc((size_t)NN * 4 * sizeof(float));
    unsigned short* Wt  = (unsigned short*)alloc(3 * 65536 * sizeof(unsigned short));
    unsigned short* Wt2 = (unsigned short*)alloc(65536 * sizeof(unsigned short));
    float* cvec    = (float*)alloc(256 * sizeof(float));
    float* bnsums  = (float*)alloc(512 * sizeof(float));
    float* bnscale = (float*)alloc(256 * sizeof(float));
    float* bnshift = (float*)alloc(256 * sizeof(float));

    // CSR build (graph identical for all layers)
    hipMemsetAsync(cnt, 0, NN * sizeof(int), stream);
    k_xcast<<<12500, 256, 0, stream>>>(x, xbf);
    k_hist<<<(NE + 255) / 256, 256, 0, stream>>>(dst, cnt);
    k_scan1<<<SCB, 256, 0, stream>>>(cnt, loc, bsum);
    k_scan2<<<1, 256, 0, stream>>>(bsum, boff, rowptr);
    k_scan3<<<SCB, 256, 0, stream>>>(loc, boff, rowptr, cursor);
    k_scatter<<<(NE + 255) / 256, 256, 0, stream>>>(src, dst, cursor, ssrc);
    k_prepw<<<768, 256, 0, stream>>>(W1, W2, W3, Wt);

    const int GB = (NN + 63) / 64;  // 782
    const int NB = NN / 4;          // 12500

    // ---- layer 1 (no BN on input: fold with sc=null -> identity, c=0) ----
    k_fold<<<256, 256, 0, stream>>>(Wt, nullptr, nullptr, Wt2, cvec);
    k_gemm<<<GB, 256, 0, stream>>>(xbf, Wt2, cvec, al1, ar1, feat16, el, er);
    k_agg<<<NB, 256, 0, stream>>>(feat16, el, er, rowptr, ssrc, xbf,
                                  nullptr, nullptr, 0, b1, 1, hbuf, nullptr, 0);
    hipMemsetAsync(bnsums, 0, 512 * sizeof(float), stream);
    k_bnstats<<<256, 256, 0, stream>>>(hbuf, bnsums);
    k_bnfinal<<<1, 256, 0, stream>>>(bnsums, g1, be1, bnscale, bnshift);

    // ---- layer 2 ----
    k_fold<<<256, 256, 0, stream>>>(Wt + 65536, bnscale, bnshift, Wt2, cvec);
    k_gemm<<<GB, 256, 0, stream>>>(hbuf, Wt2, cvec, al2, ar2, feat16, el, er);
    k_agg<<<NB, 256, 0, stream>>>(feat16, el, er, rowptr, ssrc, hbuf,
                                  bnscale, bnshift, 1, b2, 1, hbuf, nullptr, 0);
    hipMemsetAsync(bnsums, 0, 512 * sizeof(float), stream);
    k_bnstats<<<256, 256, 0, stream>>>(hbuf, bnsums);
    k_bnfinal<<<1, 256, 0, stream>>>(bnsums, g2, be2, bnscale, bnshift);

    // ---- layer 3 ----
    k_fold<<<256, 256, 0, stream>>>(Wt + 131072, bnscale, bnshift, Wt2, cvec);
    k_gemm<<<GB, 256, 0, stream>>>(hbuf, Wt2, cvec, al3, ar3, feat16, el, er);
    k_agg<<<NB, 256, 0, stream>>>(feat16, el, er, rowptr, ssrc, hbuf,
                                  bnscale, bnshift, 1, b3, 0, nullptr, out, 1);
}

// Round 6
// 610.081 us; speedup vs baseline: 1.0323x; 1.0323x over previous
//
#include <hip/hip_runtime.h>

constexpr int NN = 50000;     // nodes
constexpr int NE = 800000;    // edges
constexpr float SLOPE_A = 0.2f;   // attention leaky_relu
constexpr float SLOPE_R = 0.01f;  // activation leaky_relu
constexpr int SCB = 196;      // scan blocks: 196*256 = 50176 >= NN

typedef __attribute__((ext_vector_type(8))) short bf16x8;
typedef __attribute__((ext_vector_type(4))) float f32x4;

__device__ __forceinline__ unsigned short f2bf(float f) {
    union { float f; unsigned u; } v; v.f = f;
    unsigned u = v.u;
    unsigned r = u + 0x7fffu + ((u >> 16) & 1u);  // round-to-nearest-even
    return (unsigned short)(r >> 16);
}
__device__ __forceinline__ float bf2f(unsigned short s) {
    union { unsigned u; float f; } v; v.u = ((unsigned)s) << 16;
    return v.f;
}

// ---------------- CSR build ----------------
__global__ void k_hist(const int* __restrict__ dst, int* __restrict__ cnt) {
    int i = blockIdx.x * 256 + threadIdx.x;
    if (i < NE) atomicAdd(&cnt[dst[i]], 1);
}

__global__ void k_scan1(const int* __restrict__ cnt, int* __restrict__ loc,
                        int* __restrict__ bsum) {
    __shared__ int sh[256];
    int t = threadIdx.x;
    int i = blockIdx.x * 256 + t;
    int v = (i < NN) ? cnt[i] : 0;
    sh[t] = v;
    __syncthreads();
    for (int off = 1; off < 256; off <<= 1) {
        int tmp = (t >= off) ? sh[t - off] : 0;
        __syncthreads();
        sh[t] += tmp;
        __syncthreads();
    }
    loc[i] = sh[t] - v;
    if (t == 255) bsum[blockIdx.x] = sh[255];
}

__global__ void k_scan2(const int* __restrict__ bsum, int* __restrict__ boff,
                        int* __restrict__ rowptr) {
    __shared__ int sh[256];
    int t = threadIdx.x;
    int v = (t < SCB) ? bsum[t] : 0;
    sh[t] = v;
    __syncthreads();
    for (int off = 1; off < 256; off <<= 1) {
        int tmp = (t >= off) ? sh[t - off] : 0;
        __syncthreads();
        sh[t] += tmp;
        __syncthreads();
    }
    if (t < SCB) boff[t] = sh[t] - v;
    if (t == 255) rowptr[NN] = sh[255];
}

__global__ void k_scan3(const int* __restrict__ loc, const int* __restrict__ boff,
                        int* __restrict__ rowptr, int* __restrict__ cursor) {
    int i = blockIdx.x * 256 + threadIdx.x;
    if (i < NN) {
        int r = loc[i] + boff[blockIdx.x];
        rowptr[i] = r;
        cursor[i] = r;
    }
}

__global__ void k_scatter(const int* __restrict__ src, const int* __restrict__ dst,
                          int* __restrict__ cursor, int* __restrict__ ssrc) {
    int i = blockIdx.x * 256 + threadIdx.x;
    if (i < NE) {
        int d = dst[i];
        int pos = atomicAdd(&cursor[d], 1);
        ssrc[pos] = src[i];
    }
}

// ---------------- W -> bf16 transposed (Wt[n][k] = W[k][n]) ----------------
__global__ void k_prepw(const float* __restrict__ W1, const float* __restrict__ W2,
                        const float* __restrict__ W3, unsigned short* __restrict__ Wt) {
    int b = blockIdx.x;          // 768 = 3 layers * 256 k-rows
    int L = b >> 8, k = b & 255;
    const float* W = (L == 0) ? W1 : ((L == 1) ? W2 : W3);
    int j = threadIdx.x;
    Wt[L * 65536 + j * 256 + k] = f2bf(W[k * 256 + j]);
}

// ---------------- fold: Wfrag (MFMA B-fragment order, BN scale folded) + cvec ----
// blocks 0..511: Wfrag; blocks 512..767: cvec[n] = sum_k sh[k]*Wt[n][k]
// Wfrag[((w*8+kc)*4+j)*512 + lane*8 + t] = sc[k]*Wt[64w+16j+mm][k], k=kc*32+q*8+t
__global__ void k_fold(const unsigned short* __restrict__ Wt, const float* __restrict__ sc,
                       const float* __restrict__ sh, unsigned short* __restrict__ Wfrag,
                       float* __restrict__ cvec) {
    int b = blockIdx.x;
    if (b < 512) {
        int gid = b * 256 + threadIdx.x;   // one thread = 8 shorts
        int lane = gid & 63;
        int frag = gid >> 6;
        int j = frag & 3, kc = (frag >> 2) & 7, w = frag >> 5;
        int mm = lane & 15, q = lane >> 4;
        int n = 64 * w + 16 * j + mm;
        int k0 = kc * 32 + q * 8;
        const unsigned short* srcp = Wt + n * 256 + k0;
        unsigned short o[8];
        if (sc) {
#pragma unroll
            for (int t = 0; t < 8; t++)
                o[t] = f2bf(sc[k0 + t] * bf2f(srcp[t]));
        } else {
#pragma unroll
            for (int t = 0; t < 8; t++) o[t] = srcp[t];
        }
        *(uint4*)(Wfrag + (size_t)gid * 8) = *(const uint4*)o;
    } else {
        __shared__ float red[256];
        int n = b - 512;
        int k = threadIdx.x;
        red[k] = sh[k] * bf2f(Wt[n * 256 + k]);
        __syncthreads();
        for (int off = 128; off > 0; off >>= 1) {
            if (k < off) red[k] += red[k + off];
            __syncthreads();
        }
        if (k == 0) cvec[n] = red[0];
    }
}

// ---------------- GEMM: feat = A @ Wfrag (+cvec)  (bf16 MFMA, fp32 acc) --------
// block: 256 thr = 4 waves; tile 64 rows x 256 cols; wave w owns cols [64w,64w+64)
// = head w. B loads fully coalesced from fragment-ordered Wfrag (L2-resident).
// Epilogue: +cvec, fused el/er, LDS-bounce coalesced bf16 feat store.
__launch_bounds__(256, 2)
__global__ void k_gemm(const void* __restrict__ Araw, int af32,
                       const unsigned short* __restrict__ Wfrag,
                       const float* __restrict__ cvec,
                       const float* __restrict__ al, const float* __restrict__ ar,
                       unsigned short* __restrict__ feat16, float* __restrict__ el,
                       float* __restrict__ er) {
    constexpr int AP = 264;  // A lds pitch in bf16 elems (row start 16B-aligned)
    __shared__ __align__(16) unsigned short Alds[64 * AP];
    const int tid = threadIdx.x;
    const int rowbase = blockIdx.x * 64;

    // stage A: 64 rows x 256 bf16
    if (af32) {
        const float* A = (const float*)Araw;
        int r = tid >> 6;
        int c4 = tid & 63;
        for (int it = 0; it < 16; it++) {
            int rr = it * 4 + r;
            int gr = rowbase + rr;
            float4 v = make_float4(0.f, 0.f, 0.f, 0.f);
            if (gr < NN) v = *(const float4*)(A + (size_t)gr * 256 + c4 * 4);
            ushort4 pv;
            pv.x = f2bf(v.x); pv.y = f2bf(v.y); pv.z = f2bf(v.z); pv.w = f2bf(v.w);
            *(ushort4*)(&Alds[rr * AP + c4 * 4]) = pv;
        }
    } else {
        const unsigned short* A = (const unsigned short*)Araw;
        for (int it = 0; it < 8; it++) {
            int idx = it * 256 + tid;
            int rr = idx >> 5;
            int c16 = idx & 31;
            int gr = rowbase + rr;
            uint4 v = make_uint4(0u, 0u, 0u, 0u);
            if (gr < NN) v = *(const uint4*)(A + (size_t)gr * 256 + c16 * 8);
            *(uint4*)(&Alds[rr * AP + c16 * 8]) = v;
        }
    }
    __syncthreads();

    f32x4 acc[4][4];
    for (int i = 0; i < 4; i++)
        for (int j = 0; j < 4; j++)
            acc[i][j] = (f32x4){0.f, 0.f, 0.f, 0.f};

    const int lane = tid & 63, w = tid >> 6;
    const int mm = lane & 15, q = lane >> 4;

    // coalesced B: wave w, chunk kc, block j at Wfrag[((w*8+kc)*4+j)*512 + lane*8]
    const unsigned short* bbase = Wfrag + ((size_t)w * 8 * 4) * 512 + (size_t)lane * 8;

#pragma unroll
    for (int kc = 0; kc < 8; kc++) {
        bf16x8 a[4], b[4];
        for (int i = 0; i < 4; i++)
            a[i] = *(const bf16x8*)(&Alds[(16 * i + mm) * AP + kc * 32 + q * 8]);
        for (int j = 0; j < 4; j++)
            b[j] = *(const bf16x8*)(bbase + (size_t)(kc * 4 + j) * 512);
        for (int i = 0; i < 4; i++)
            for (int j = 0; j < 4; j++)
                acc[i][j] = __builtin_amdgcn_mfma_f32_16x16x32_bf16(a[i], b[j], acc[i][j], 0, 0, 0);
    }
    __syncthreads();   // all waves done reading Alds before epilogue reuses it

    // ---- folded-BN column offset ----
    if (cvec) {
        float cv[4];
        for (int j = 0; j < 4; j++) cv[j] = cvec[64 * w + 16 * j + mm];
        for (int i = 0; i < 4; i++)
            for (int j = 0; j < 4; j++)
                for (int r = 0; r < 4; r++)
                    acc[i][j][r] += cv[j];
    }

    // ---- fused el/er: head w cols are exactly this wave's 64 cols ----
    float alv[4], arv[4];
    for (int j = 0; j < 4; j++) {
        alv[j] = al[w * 64 + 16 * j + mm];
        arv[j] = ar[w * 64 + 16 * j + mm];
    }
    for (int i = 0; i < 4; i++) {
        for (int r = 0; r < 4; r++) {
            int gr = rowbase + 16 * i + q * 4 + r;
            float se = 0.f, sr = 0.f;
            for (int j = 0; j < 4; j++) {
                se += acc[i][j][r] * alv[j];
                sr += acc[i][j][r] * arv[j];
            }
            for (int off = 1; off < 16; off <<= 1) {
                se += __shfl_xor(se, off, 64);
                sr += __shfl_xor(sr, off, 64);
            }
            if (mm == 0 && gr < NN) {
                el[gr * 4 + w] = se;
                er[gr * 4 + w] = sr;
            }
        }
    }

    // ---- LDS-bounce feat16 store (C/D layout: col=lane&15, row=(lane>>4)*4+reg) ----
    for (int i = 0; i < 4; i++)
        for (int j = 0; j < 4; j++) {
            int gc = 64 * w + 16 * j + mm;
            for (int r = 0; r < 4; r++) {
                int rr = 16 * i + q * 4 + r;
                Alds[rr * AP + gc] = f2bf(acc[i][j][r]);
            }
        }
    __syncthreads();
    for (int it = 0; it < 8; it++) {
        int idx = it * 256 + tid;
        int rr = idx >> 5;
        int c16 = idx & 31;
        int gr = rowbase + rr;
        if (gr < NN)
            *(uint4*)(feat16 + (size_t)gr * 256 + c16 * 8) = *(const uint4*)(&Alds[rr * AP + c16 * 8]);
    }
}

// ---------------- per-dst softmax + weighted aggregation (bf16 gather) ----------------
// TWO waves per destination node (edge list split, LDS combine); lane l owns
// channels [4l,4l+4); head h = l>>4. No-max softmax. Predicated unroll-8.
__launch_bounds__(256)
__global__ void k_agg(const unsigned short* __restrict__ feat16, const float* __restrict__ el,
                      const float* __restrict__ er, const int* __restrict__ rowptr,
                      const int* __restrict__ ssrc,
                      const unsigned short* __restrict__ residh, const float* __restrict__ residf,
                      const float* __restrict__ bnscale, const float* __restrict__ bnshift,
                      int use_bn, const float* __restrict__ bias, int act,
                      unsigned short* __restrict__ outh, float* __restrict__ outf,
                      int final_mean) {
    __shared__ float comb[2][64][5];
    int tid = threadIdx.x;
    int nl = tid >> 7;              // node within block (0/1)
    int v = (tid >> 6) & 1;         // wave pair index
    int l = tid & 63;
    int n = __builtin_amdgcn_readfirstlane(blockIdx.x * 2 + nl);
    int h = l >> 4;
    int beg = rowptr[n], end = rowptr[n + 1];
    float erh = er[n * 4 + h];

    float d = 0.f;
    float4 acc = make_float4(0.f, 0.f, 0.f, 0.f);

    for (int e = beg + 8 * v; e < end; e += 16) {
        int ss[8];
        float cc[8];
        ushort4 ff[8];
#pragma unroll
        for (int j = 0; j < 8; j++) {
            int ee = e + j;
            ss[j] = ssrc[(ee < end) ? ee : beg];
        }
#pragma unroll
        for (int j = 0; j < 8; j++)
            cc[j] = el[ss[j] * 4 + h];
#pragma unroll
        for (int j = 0; j < 8; j++)
            ff[j] = *(const ushort4*)(feat16 + (size_t)ss[j] * 256 + l * 4);
#pragma unroll
        for (int j = 0; j < 8; j++) {
            float sc = cc[j] + erh;
            sc = (sc > 0.f) ? sc : SLOPE_A * sc;
            float wgt = ((e + j) < end) ? __expf(sc) : 0.f;
            d += wgt;
            acc.x += bf2f(ff[j].x) * wgt;
            acc.y += bf2f(ff[j].y) * wgt;
            acc.z += bf2f(ff[j].z) * wgt;
            acc.w += bf2f(ff[j].w) * wgt;
        }
    }

    if (v == 1) {
        comb[nl][l][0] = acc.x; comb[nl][l][1] = acc.y;
        comb[nl][l][2] = acc.z; comb[nl][l][3] = acc.w;
        comb[nl][l][4] = d;
    }
    __syncthreads();
    if (v == 1) return;
    acc.x += comb[nl][l][0]; acc.y += comb[nl][l][1];
    acc.z += comb[nl][l][2]; acc.w += comb[nl][l][3];
    d += comb[nl][l][4];

    float invd = 1.f / fmaxf(d, 1e-9f);
    acc.x *= invd; acc.y *= invd; acc.z *= invd; acc.w *= invd;

    // residual (+BN) + bias
    float4 r;
    if (residf) {
        r = *(const float4*)(residf + (size_t)n * 256 + l * 4);
    } else {
        ushort4 rv = *(const ushort4*)(residh + (size_t)n * 256 + l * 4);
        r = make_float4(bf2f(rv.x), bf2f(rv.y), bf2f(rv.z), bf2f(rv.w));
    }
    if (use_bn) {
        float4 sc4 = *(const float4*)(bnscale + l * 4);
        float4 sh4 = *(const float4*)(bnshift + l * 4);
        r.x = r.x * sc4.x + sh4.x;
        r.y = r.y * sc4.y + sh4.y;
        r.z = r.z * sc4.z + sh4.z;
        r.w = r.w * sc4.w + sh4.w;
    }
    float4 bb = *(const float4*)(bias + l * 4);
    acc.x += r.x + bb.x; acc.y += r.y + bb.y;
    acc.z += r.z + bb.z; acc.w += r.w + bb.w;
    if (act) {
        acc.x = (acc.x > 0.f) ? acc.x : SLOPE_R * acc.x;
        acc.y = (acc.y > 0.f) ? acc.y : SLOPE_R * acc.y;
        acc.z = (acc.z > 0.f) ? acc.z : SLOPE_R * acc.z;
        acc.w = (acc.w > 0.f) ? acc.w : SLOPE_R * acc.w;
    }

    if (!final_mean) {
        ushort4 p;
        p.x = f2bf(acc.x); p.y = f2bf(acc.y); p.z = f2bf(acc.z); p.w = f2bf(acc.w);
        *(ushort4*)(outh + (size_t)n * 256 + l * 4) = p;
    } else {
        acc.x += __shfl_xor(acc.x, 16, 64); acc.x += __shfl_xor(acc.x, 32, 64);
        acc.y += __shfl_xor(acc.y, 16, 64); acc.y += __shfl_xor(acc.y, 32, 64);
        acc.z += __shfl_xor(acc.z, 16, 64); acc.z += __shfl_xor(acc.z, 32, 64);
        acc.w += __shfl_xor(acc.w, 16, 64); acc.w += __shfl_xor(acc.w, 32, 64);
        if (l < 16) {
            acc.x *= 0.25f; acc.y *= 0.25f; acc.z *= 0.25f; acc.w *= 0.25f;
            *(float4*)(outf + (size_t)n * 64 + l * 4) = acc;
        }
    }
}

// ---------------- BatchNorm stats (bf16 input) ----------------
__global__ void k_bnstats(const unsigned short* __restrict__ hh, float* __restrict__ sums) {
    int t = threadIdx.x;
    int b = blockIdx.x;
    int r0 = b * 196, r1 = min(r0 + 196, NN);
    float s = 0.f, s2 = 0.f;
    for (int r = r0; r < r1; r++) {
        float v = bf2f(hh[(size_t)r * 256 + t]);
        s += v; s2 += v * v;
    }
    atomicAdd(&sums[t], s);
    atomicAdd(&sums[256 + t], s2);
}

__global__ void k_bnfinal(const float* __restrict__ sums, const float* __restrict__ g,
                          const float* __restrict__ be, float* __restrict__ scale,
                          float* __restrict__ shift) {
    int t = threadIdx.x;
    float mu = sums[t] * (1.f / NN);
    float var = sums[256 + t] * (1.f / NN) - mu * mu;
    float rs = rsqrtf(var + 1e-5f);
    float sc = rs * g[t];
    scale[t] = sc;
    shift[t] = be[t] - mu * sc;
}

// ---------------- launcher ----------------
extern "C" void kernel_launch(void* const* d_in, const int* in_sizes, int n_in,
                              void* d_out, int out_size, void* d_ws, size_t ws_size,
                              hipStream_t stream) {
    const float* x   = (const float*)d_in[0];
    const int* src   = (const int*)d_in[1];
    const int* dst   = (const int*)d_in[2];
    const float* W1  = (const float*)d_in[3];
    const float* al1 = (const float*)d_in[4];
    const float* ar1 = (const float*)d_in[5];
    const float* b1  = (const float*)d_in[6];
    const float* W2  = (const float*)d_in[7];
    const float* al2 = (const float*)d_in[8];
    const float* ar2 = (const float*)d_in[9];
    const float* b2  = (const float*)d_in[10];
    const float* W3  = (const float*)d_in[11];
    const float* al3 = (const float*)d_in[12];
    const float* ar3 = (const float*)d_in[13];
    const float* b3  = (const float*)d_in[14];
    const float* g1  = (const float*)d_in[15];
    const float* be1 = (const float*)d_in[16];
    const float* g2  = (const float*)d_in[17];
    const float* be2 = (const float*)d_in[18];
    float* out = (float*)d_out;

    char* ws = (char*)d_ws;
    size_t off = 0;
    auto alloc = [&](size_t bytes) {
        void* p = ws + off;
        off += (bytes + 255) & ~(size_t)255;
        return p;
    };
    int* rowptr = (int*)alloc((NN + 1) * sizeof(int));
    int* cursor = (int*)alloc(NN * sizeof(int));
    int* cnt    = (int*)alloc(SCB * 256 * sizeof(int));
    int* loc    = (int*)alloc(SCB * 256 * sizeof(int));
    int* bsum   = (int*)alloc(SCB * sizeof(int));
    int* boff   = (int*)alloc(SCB * sizeof(int));
    int* ssrc   = (int*)alloc(NE * sizeof(int));
    unsigned short* feat16 = (unsigned short*)alloc((size_t)NN * 256 * sizeof(unsigned short));
    unsigned short* hbuf   = (unsigned short*)alloc((size_t)NN * 256 * sizeof(unsigned short));
    float* el   = (float*)alloc((size_t)NN * 4 * sizeof(float));
    float* er   = (float*)alloc((size_t)NN * 4 * sizeof(float));
    unsigned short* Wt     = (unsigned short*)alloc(3 * 65536 * sizeof(unsigned short));
    unsigned short* Wfrag1 = (unsigned short*)alloc(131072 * sizeof(unsigned short) * 8);
    unsigned short* Wfrag2 = (unsigned short*)alloc(131072 * sizeof(unsigned short) * 8);
    float* cvec    = (float*)alloc(256 * sizeof(float));
    float* bnsums  = (float*)alloc(512 * sizeof(float));
    float* bnscale = (float*)alloc(256 * sizeof(float));
    float* bnshift = (float*)alloc(256 * sizeof(float));

    // CSR build (graph identical for all layers)
    hipMemsetAsync(cnt, 0, NN * sizeof(int), stream);
    k_hist<<<(NE + 255) / 256, 256, 0, stream>>>(dst, cnt);
    k_scan1<<<SCB, 256, 0, stream>>>(cnt, loc, bsum);
    k_scan2<<<1, 256, 0, stream>>>(bsum, boff, rowptr);
    k_scan3<<<SCB, 256, 0, stream>>>(loc, boff, rowptr, cursor);
    k_scatter<<<(NE + 255) / 256, 256, 0, stream>>>(src, dst, cursor, ssrc);
    k_prepw<<<768, 256, 0, stream>>>(W1, W2, W3, Wt);
    k_fold<<<512, 256, 0, stream>>>(Wt, nullptr, nullptr, Wfrag1, nullptr);

    const int GB = (NN + 63) / 64;  // 782
    const int NB = NN / 2;          // 25000 (2 nodes per block, 2 waves/node)

    // ---- layer 1 ----
    k_gemm<<<GB, 256, 0, stream>>>(x, 1, Wfrag1, nullptr, al1, ar1, feat16, el, er);
    k_agg<<<NB, 256, 0, stream>>>(feat16, el, er, rowptr, ssrc, nullptr, x,
                                  nullptr, nullptr, 0, b1, 1, hbuf, nullptr, 0);
    hipMemsetAsync(bnsums, 0, 512 * sizeof(float), stream);
    k_bnstats<<<256, 256, 0, stream>>>(hbuf, bnsums);
    k_bnfinal<<<1, 256, 0, stream>>>(bnsums, g1, be1, bnscale, bnshift);
    k_fold<<<768, 256, 0, stream>>>(Wt + 65536, bnscale, bnshift, Wfrag2, cvec);

    // ---- layer 2 ----
    k_gemm<<<GB, 256, 0, stream>>>(hbuf, 0, Wfrag2, cvec, al2, ar2, feat16, el, er);
    k_agg<<<NB, 256, 0, stream>>>(feat16, el, er, rowptr, ssrc, hbuf, nullptr,
                                  bnscale, bnshift, 1, b2, 1, hbuf, nullptr, 0);
    hipMemsetAsync(bnsums, 0, 512 * sizeof(float), stream);
    k_bnstats<<<256, 256, 0, stream>>>(hbuf, bnsums);
    k_bnfinal<<<1, 256, 0, stream>>>(bnsums, g2, be2, bnscale, bnshift);
    k_fold<<<768, 256, 0, stream>>>(Wt + 131072, bnscale, bnshift, Wfrag2, cvec);

    // ---- layer 3 ----
    k_gemm<<<GB, 256, 0, stream>>>(hbuf, 0, Wfrag2, cvec, al3, ar3, feat16, el, er);
    k_agg<<<NB, 256, 0, stream>>>(feat16, el, er, rowptr, ssrc, hbuf, nullptr,
                                  bnscale, bnshift, 1, b3, 0, nullptr, out, 1);
}

// Round 8
// 577.164 us; speedup vs baseline: 1.0911x; 1.0570x over previous
//
#include <hip/hip_runtime.h>

constexpr int NN = 50000;     // nodes
constexpr int NE = 800000;    // edges
constexpr float SLOPE_A = 0.2f;   // attention leaky_relu
constexpr float SLOPE_R = 0.01f;  // activation leaky_relu
constexpr int SCB = 196;      // scan blocks: 196*256 = 50176 >= NN

typedef __attribute__((ext_vector_type(8))) short bf16x8;
typedef __attribute__((ext_vector_type(4))) float f32x4;

__device__ __forceinline__ unsigned short f2bf(float f) {
    union { float f; unsigned u; } v; v.f = f;
    unsigned u = v.u;
    unsigned r = u + 0x7fffu + ((u >> 16) & 1u);  // round-to-nearest-even
    return (unsigned short)(r >> 16);
}
__device__ __forceinline__ float bf2f(unsigned short s) {
    union { unsigned u; float f; } v; v.u = ((unsigned)s) << 16;
    return v.f;
}

// ---------------- CSR build ----------------
__global__ void k_hist(const int* __restrict__ dst, int* __restrict__ cnt) {
    int i = blockIdx.x * 256 + threadIdx.x;
    if (i < NE) atomicAdd(&cnt[dst[i]], 1);
}

__global__ void k_scan1(const int* __restrict__ cnt, int* __restrict__ loc,
                        int* __restrict__ bsum) {
    __shared__ int sh[256];
    int t = threadIdx.x;
    int i = blockIdx.x * 256 + t;
    int v = (i < NN) ? cnt[i] : 0;
    sh[t] = v;
    __syncthreads();
    for (int off = 1; off < 256; off <<= 1) {
        int tmp = (t >= off) ? sh[t - off] : 0;
        __syncthreads();
        sh[t] += tmp;
        __syncthreads();
    }
    loc[i] = sh[t] - v;
    if (t == 255) bsum[blockIdx.x] = sh[255];
}

__global__ void k_scan2(const int* __restrict__ bsum, int* __restrict__ boff,
                        int* __restrict__ rowptr) {
    __shared__ int sh[256];
    int t = threadIdx.x;
    int v = (t < SCB) ? bsum[t] : 0;
    sh[t] = v;
    __syncthreads();
    for (int off = 1; off < 256; off <<= 1) {
        int tmp = (t >= off) ? sh[t - off] : 0;
        __syncthreads();
        sh[t] += tmp;
        __syncthreads();
    }
    if (t < SCB) boff[t] = sh[t] - v;
    if (t == 255) rowptr[NN] = sh[255];
}

__global__ void k_scan3(const int* __restrict__ loc, const int* __restrict__ boff,
                        int* __restrict__ rowptr, int* __restrict__ cursor) {
    int i = blockIdx.x * 256 + threadIdx.x;
    if (i < NN) {
        int r = loc[i] + boff[blockIdx.x];
        rowptr[i] = r;
        cursor[i] = r;
    }
}

__global__ void k_scatter(const int* __restrict__ src, const int* __restrict__ dst,
                          int* __restrict__ cursor, int* __restrict__ ssrc) {
    int i = blockIdx.x * 256 + threadIdx.x;
    if (i < NE) {
        int d = dst[i];
        int pos = atomicAdd(&cursor[d], 1);
        ssrc[pos] = src[i];
    }
}

// ---------------- W -> bf16 transposed (Wt[n][k] = W[k][n]) ----------------
__global__ void k_prepw(const float* __restrict__ W1, const float* __restrict__ W2,
                        const float* __restrict__ W3, unsigned short* __restrict__ Wt) {
    int b = blockIdx.x;          // 768 = 3 layers * 256 k-rows
    int L = b >> 8, k = b & 255;
    const float* W = (L == 0) ? W1 : ((L == 1) ? W2 : W3);
    int j = threadIdx.x;
    Wt[L * 65536 + j * 256 + k] = f2bf(W[k * 256 + j]);
}

// ---------------- fold: Wfrag (MFMA B-fragment order, BN scale folded) + cvec ----
// blocks 0..31: Wfrag (128 frags x 64 lanes x 8 shorts = 65536 shorts);
// blocks 32..287: cvec[n] = sum_k sh[k]*Wt[n][k], n = b-32.
__global__ void k_fold(const unsigned short* __restrict__ Wt, const float* __restrict__ sc,
                       const float* __restrict__ sh, unsigned short* __restrict__ Wfrag,
                       float* __restrict__ cvec) {
    int b = blockIdx.x;
    if (b < 32) {
        int gid = b * 256 + threadIdx.x;   // one thread = 8 shorts; gid < 8192
        int lane = gid & 63;
        int frag = gid >> 6;               // 0..127
        int j = frag & 3, kc = (frag >> 2) & 7, w = frag >> 5;   // w in 0..3
        int mm = lane & 15, q = lane >> 4;
        int n = 64 * w + 16 * j + mm;
        int k0 = kc * 32 + q * 8;
        const unsigned short* srcp = Wt + n * 256 + k0;
        unsigned short o[8];
        if (sc) {
#pragma unroll
            for (int t = 0; t < 8; t++)
                o[t] = f2bf(sc[k0 + t] * bf2f(srcp[t]));
        } else {
#pragma unroll
            for (int t = 0; t < 8; t++) o[t] = srcp[t];
        }
        *(uint4*)(Wfrag + (size_t)gid * 8) = *(const uint4*)o;
    } else {
        __shared__ float red[256];
        int n = b - 32;
        int k = threadIdx.x;
        red[k] = sh[k] * bf2f(Wt[n * 256 + k]);
        __syncthreads();
        for (int off = 128; off > 0; off >>= 1) {
            if (k < off) red[k] += red[k + off];
            __syncthreads();
        }
        if (k == 0) cvec[n] = red[0];
    }
}

// ---------------- foldlr: wl/wr matvec weights as one MFMA B-fragment ----------
// wl[k][h] = sc[k] * sum_d Wt[64h+d][k]*al[h][d]; cols n=2h+s (s=0:l,1:r), n>=8 zero.
// offlr[n] = sum_d cvec[64h+d]*a[h][d]  (attention dot of the BN shift offset)
__global__ void k_foldlr(const unsigned short* __restrict__ Wt, const float* __restrict__ sc,
                         const float* __restrict__ cvec, const float* __restrict__ al,
                         const float* __restrict__ ar, unsigned short* __restrict__ wlrfrag,
                         float* __restrict__ offlr) {
    __shared__ float lw[256][8];
    int k = threadIdx.x;
    float scv = sc ? sc[k] : 1.f;
    for (int h = 0; h < 4; h++) {
        float sl = 0.f, sr = 0.f;
        for (int d = 0; d < 64; d++) {
            float wv = bf2f(Wt[(64 * h + d) * 256 + k]);
            sl += wv * al[h * 64 + d];
            sr += wv * ar[h * 64 + d];
        }
        lw[k][2 * h] = scv * sl;
        lw[k][2 * h + 1] = scv * sr;
    }
    __syncthreads();
    int kc = k >> 5, rem = k & 31, q = rem >> 3, t = rem & 7;  // k = kc*32+q*8+t
    for (int mm = 0; mm < 16; mm++) {
        unsigned short v = 0;
        if (mm < 8) v = f2bf(lw[k][mm]);
        wlrfrag[kc * 512 + (q * 16 + mm) * 8 + t] = v;
    }
    if (k < 8) {
        float o = 0.f;
        if (cvec) {
            int h = k >> 1;
            const float* a = (k & 1) ? ar : al;
            for (int d = 0; d < 64; d++) o += cvec[64 * h + d] * a[h * 64 + d];
        }
        offlr[k] = o;
    }
}

// ---------------- GEMM: feat = A @ Wfrag (+cvec); el/er via extra MFMA --------
// block: 256 thr = 4 waves; tile 64 rows x 256 cols; wave w owns cols [64w,64w+64).
// Wave 0 additionally computes the 8-col el/er matvec with one extra B-frag.
__launch_bounds__(256, 2)
__global__ void k_gemm(const void* __restrict__ Araw, int af32,
                       const unsigned short* __restrict__ Wfrag,
                       const float* __restrict__ cvec,
                       const unsigned short* __restrict__ wlrfrag,
                       const float* __restrict__ offlr,
                       unsigned short* __restrict__ feat16, float* __restrict__ el,
                       float* __restrict__ er) {
    constexpr int AP = 264;  // A lds pitch in bf16 elems (row start 16B-aligned)
    __shared__ __align__(16) unsigned short Alds[64 * AP];
    const int tid = threadIdx.x;
    const int rowbase = blockIdx.x * 64;

    // stage A: 64 rows x 256 bf16
    if (af32) {
        const float* A = (const float*)Araw;
        int r = tid >> 6;
        int c4 = tid & 63;
        for (int it = 0; it < 16; it++) {
            int rr = it * 4 + r;
            int gr = rowbase + rr;
            float4 v = make_float4(0.f, 0.f, 0.f, 0.f);
            if (gr < NN) v = *(const float4*)(A + (size_t)gr * 256 + c4 * 4);
            ushort4 pv;
            pv.x = f2bf(v.x); pv.y = f2bf(v.y); pv.z = f2bf(v.z); pv.w = f2bf(v.w);
            *(ushort4*)(&Alds[rr * AP + c4 * 4]) = pv;
        }
    } else {
        const unsigned short* A = (const unsigned short*)Araw;
        for (int it = 0; it < 8; it++) {
            int idx = it * 256 + tid;
            int rr = idx >> 5;
            int c16 = idx & 31;
            int gr = rowbase + rr;
            uint4 v = make_uint4(0u, 0u, 0u, 0u);
            if (gr < NN) v = *(const uint4*)(A + (size_t)gr * 256 + c16 * 8);
            *(uint4*)(&Alds[rr * AP + c16 * 8]) = v;
        }
    }
    __syncthreads();

    f32x4 acc[4][4];
    for (int i = 0; i < 4; i++)
        for (int j = 0; j < 4; j++)
            acc[i][j] = (f32x4){0.f, 0.f, 0.f, 0.f};
    f32x4 accLR[4];
    for (int i = 0; i < 4; i++) accLR[i] = (f32x4){0.f, 0.f, 0.f, 0.f};

    const int lane = tid & 63, w = tid >> 6;
    const int mm = lane & 15, q = lane >> 4;

    const unsigned short* bbase = Wfrag + ((size_t)w * 8 * 4) * 512 + (size_t)lane * 8;

#pragma unroll
    for (int kc = 0; kc < 8; kc++) {
        bf16x8 a[4], b[4];
        for (int i = 0; i < 4; i++)
            a[i] = *(const bf16x8*)(&Alds[(16 * i + mm) * AP + kc * 32 + q * 8]);
        for (int j = 0; j < 4; j++)
            b[j] = *(const bf16x8*)(bbase + (size_t)(kc * 4 + j) * 512);
        for (int i = 0; i < 4; i++)
            for (int j = 0; j < 4; j++)
                acc[i][j] = __builtin_amdgcn_mfma_f32_16x16x32_bf16(a[i], b[j], acc[i][j], 0, 0, 0);
        if (w == 0) {
            bf16x8 blr = *(const bf16x8*)(wlrfrag + kc * 512 + lane * 8);
            for (int i = 0; i < 4; i++)
                accLR[i] = __builtin_amdgcn_mfma_f32_16x16x32_bf16(a[i], blr, accLR[i], 0, 0, 0);
        }
    }
    __syncthreads();   // all waves done reading Alds before epilogue reuses it

    // ---- folded-BN column offset on feat ----
    if (cvec) {
        float cv[4];
        for (int j = 0; j < 4; j++) cv[j] = cvec[64 * w + 16 * j + mm];
        for (int i = 0; i < 4; i++)
            for (int j = 0; j < 4; j++)
                for (int r = 0; r < 4; r++)
                    acc[i][j][r] += cv[j];
    }

    // ---- el/er write (wave 0, C-layout col=mm -> n=2h+s) ----
    if (w == 0 && mm < 8) {
        float off = offlr[mm];
        int h = mm >> 1;
        float* dstp = (mm & 1) ? er : el;
        for (int i = 0; i < 4; i++)
            for (int r = 0; r < 4; r++) {
                int gr = rowbase + 16 * i + q * 4 + r;
                if (gr < NN) dstp[gr * 4 + h] = accLR[i][r] + off;
            }
    }

    // ---- LDS-bounce feat16 store (C/D layout: col=lane&15, row=(lane>>4)*4+reg) ----
    for (int i = 0; i < 4; i++)
        for (int j = 0; j < 4; j++) {
            int gc = 64 * w + 16 * j + mm;
            for (int r = 0; r < 4; r++) {
                int rr = 16 * i + q * 4 + r;
                Alds[rr * AP + gc] = f2bf(acc[i][j][r]);
            }
        }
    __syncthreads();
    for (int it = 0; it < 8; it++) {
        int idx = it * 256 + tid;
        int rr = idx >> 5;
        int c16 = idx & 31;
        int gr = rowbase + rr;
        if (gr < NN)
            *(uint4*)(feat16 + (size_t)gr * 256 + c16 * 8) = *(const uint4*)(&Alds[rr * AP + c16 * 8]);
    }
}

// ---------------- per-dst softmax + weighted aggregation (bf16 gather) ----------------
// ONE wave per destination node; lane l owns channels [4l,4l+4); head h = l>>4.
// No-max softmax (scores bounded). Predicated unroll-8, 8 gathers in flight.
__launch_bounds__(256)
__global__ void k_agg(const unsigned short* __restrict__ feat16, const float* __restrict__ el,
                      const float* __restrict__ er, const int* __restrict__ rowptr,
                      const int* __restrict__ ssrc,
                      const unsigned short* __restrict__ residh, const float* __restrict__ residf,
                      const float* __restrict__ bnscale, const float* __restrict__ bnshift,
                      int use_bn, const float* __restrict__ bias, int act,
                      unsigned short* __restrict__ outh, float* __restrict__ outf,
                      int final_mean) {
    int n = __builtin_amdgcn_readfirstlane(blockIdx.x * 4 + (threadIdx.x >> 6));
    int l = threadIdx.x & 63;
    int h = l >> 4;
    int beg = rowptr[n], end = rowptr[n + 1];
    float erh = er[n * 4 + h];

    float d = 0.f;
    float4 acc = make_float4(0.f, 0.f, 0.f, 0.f);

    for (int e = beg; e < end; e += 8) {
        int ss[8];
        float cc[8];
        ushort4 ff[8];
#pragma unroll
        for (int j = 0; j < 8; j++) {
            int ee = e + j;
            ss[j] = ssrc[(ee < end) ? ee : beg];
        }
#pragma unroll
        for (int j = 0; j < 8; j++)
            cc[j] = el[ss[j] * 4 + h];
#pragma unroll
        for (int j = 0; j < 8; j++)
            ff[j] = *(const ushort4*)(feat16 + (size_t)ss[j] * 256 + l * 4);
#pragma unroll
        for (int j = 0; j < 8; j++) {
            float sc = cc[j] + erh;
            sc = (sc > 0.f) ? sc : SLOPE_A * sc;
            float wgt = ((e + j) < end) ? __expf(sc) : 0.f;
            d += wgt;
            acc.x += bf2f(ff[j].x) * wgt;
            acc.y += bf2f(ff[j].y) * wgt;
            acc.z += bf2f(ff[j].z) * wgt;
            acc.w += bf2f(ff[j].w) * wgt;
        }
    }

    float invd = 1.f / fmaxf(d, 1e-9f);
    acc.x *= invd; acc.y *= invd; acc.z *= invd; acc.w *= invd;

    // residual (+BN) + bias
    float4 r;
    if (residf) {
        r = *(const float4*)(residf + (size_t)n * 256 + l * 4);
    } else {
        ushort4 rv = *(const ushort4*)(residh + (size_t)n * 256 + l * 4);
        r = make_float4(bf2f(rv.x), bf2f(rv.y), bf2f(rv.z), bf2f(rv.w));
    }
    if (use_bn) {
        float4 sc4 = *(const float4*)(bnscale + l * 4);
        float4 sh4 = *(const float4*)(bnshift + l * 4);
        r.x = r.x * sc4.x + sh4.x;
        r.y = r.y * sc4.y + sh4.y;
        r.z = r.z * sc4.z + sh4.z;
        r.w = r.w * sc4.w + sh4.w;
    }
    float4 bb = *(const float4*)(bias + l * 4);
    acc.x += r.x + bb.x; acc.y += r.y + bb.y;
    acc.z += r.z + bb.z; acc.w += r.w + bb.w;
    if (act) {
        acc.x = (acc.x > 0.f) ? acc.x : SLOPE_R * acc.x;
        acc.y = (acc.y > 0.f) ? acc.y : SLOPE_R * acc.y;
        acc.z = (acc.z > 0.f) ? acc.z : SLOPE_R * acc.z;
        acc.w = (acc.w > 0.f) ? acc.w : SLOPE_R * acc.w;
    }

    if (!final_mean) {
        ushort4 p;
        p.x = f2bf(acc.x); p.y = f2bf(acc.y); p.z = f2bf(acc.z); p.w = f2bf(acc.w);
        *(ushort4*)(outh + (size_t)n * 256 + l * 4) = p;
    } else {
        acc.x += __shfl_xor(acc.x, 16, 64); acc.x += __shfl_xor(acc.x, 32, 64);
        acc.y += __shfl_xor(acc.y, 16, 64); acc.y += __shfl_xor(acc.y, 32, 64);
        acc.z += __shfl_xor(acc.z, 16, 64); acc.z += __shfl_xor(acc.z, 32, 64);
        acc.w += __shfl_xor(acc.w, 16, 64); acc.w += __shfl_xor(acc.w, 32, 64);
        if (l < 16) {
            acc.x *= 0.25f; acc.y *= 0.25f; acc.z *= 0.25f; acc.w *= 0.25f;
            *(float4*)(outf + (size_t)n * 64 + l * 4) = acc;
        }
    }
}

// ---------------- BatchNorm stats: vectorized partials, no atomics ----------------
__global__ void k_bnstats(const unsigned short* __restrict__ hh, float* __restrict__ pbuf) {
    __shared__ float ps[8 * 256];
    __shared__ float ps2[8 * 256];
    int t = threadIdx.x, b = blockIdx.x;
    int r8 = t >> 5, c32 = t & 31;
    int r0 = b * 196, r1 = min(r0 + 196, NN);
    float s[8], s2[8];
#pragma unroll
    for (int e = 0; e < 8; e++) { s[e] = 0.f; s2[e] = 0.f; }
    for (int r = r0 + r8; r < r1; r += 8) {
        uint4 v = *(const uint4*)(hh + (size_t)r * 256 + c32 * 8);
        const unsigned short* pv = (const unsigned short*)&v;
#pragma unroll
        for (int e = 0; e < 8; e++) {
            float f = bf2f(pv[e]);
            s[e] += f; s2[e] += f * f;
        }
    }
#pragma unroll
    for (int e = 0; e < 8; e++) {
        ps[r8 * 256 + c32 * 8 + e] = s[e];
        ps2[r8 * 256 + c32 * 8 + e] = s2[e];
    }
    __syncthreads();
    float ts = 0.f, ts2 = 0.f;
    for (int g = 0; g < 8; g++) { ts += ps[g * 256 + t]; ts2 += ps2[g * 256 + t]; }
    pbuf[b * 512 + t] = ts;
    pbuf[b * 512 + 256 + t] = ts2;
}

__global__ void k_bnfinal(const float* __restrict__ pbuf, const float* __restrict__ g,
                          const float* __restrict__ be, float* __restrict__ scale,
                          float* __restrict__ shift) {
    int t = threadIdx.x;
    float s = 0.f, s2 = 0.f;
    for (int b = 0; b < 256; b++) {
        s += pbuf[b * 512 + t];
        s2 += pbuf[b * 512 + 256 + t];
    }
    float mu = s * (1.f / NN);
    float var = s2 * (1.f / NN) - mu * mu;
    float rs = rsqrtf(var + 1e-5f);
    float sc = rs * g[t];
    scale[t] = sc;
    shift[t] = be[t] - mu * sc;
}

// ---------------- launcher ----------------
extern "C" void kernel_launch(void* const* d_in, const int* in_sizes, int n_in,
                              void* d_out, int out_size, void* d_ws, size_t ws_size,
                              hipStream_t stream) {
    const float* x   = (const float*)d_in[0];
    const int* src   = (const int*)d_in[1];
    const int* dst   = (const int*)d_in[2];
    const float* W1  = (const float*)d_in[3];
    const float* al1 = (const float*)d_in[4];
    const float* ar1 = (const float*)d_in[5];
    const float* b1  = (const float*)d_in[6];
    const float* W2  = (const float*)d_in[7];
    const float* al2 = (const float*)d_in[8];
    const float* ar2 = (const float*)d_in[9];
    const float* b2  = (const float*)d_in[10];
    const float* W3  = (const float*)d_in[11];
    const float* al3 = (const float*)d_in[12];
    const float* ar3 = (const float*)d_in[13];
    const float* b3  = (const float*)d_in[14];
    const float* g1  = (const float*)d_in[15];
    const float* be1 = (const float*)d_in[16];
    const float* g2  = (const float*)d_in[17];
    const float* be2 = (const float*)d_in[18];
    float* out = (float*)d_out;

    char* ws = (char*)d_ws;
    size_t off = 0;
    auto alloc = [&](size_t bytes) {
        void* p = ws + off;
        off += (bytes + 255) & ~(size_t)255;
        return p;
    };
    int* rowptr = (int*)alloc((NN + 1) * sizeof(int));
    int* cursor = (int*)alloc(NN * sizeof(int));
    int* cnt    = (int*)alloc(SCB * 256 * sizeof(int));
    int* loc    = (int*)alloc(SCB * 256 * sizeof(int));
    int* bsum   = (int*)alloc(SCB * sizeof(int));
    int* boff   = (int*)alloc(SCB * sizeof(int));
    int* ssrc   = (int*)alloc(NE * sizeof(int));
    unsigned short* feat16 = (unsigned short*)alloc((size_t)NN * 256 * sizeof(unsigned short));
    unsigned short* hbuf   = (unsigned short*)alloc((size_t)NN * 256 * sizeof(unsigned short));
    float* el   = (float*)alloc((size_t)NN * 4 * sizeof(float));
    float* er   = (float*)alloc((size_t)NN * 4 * sizeof(float));
    unsigned short* Wt      = (unsigned short*)alloc(3 * 65536 * sizeof(unsigned short));
    unsigned short* Wfrag1  = (unsigned short*)alloc(65536 * sizeof(unsigned short));
    unsigned short* Wfrag2  = (unsigned short*)alloc(65536 * sizeof(unsigned short));
    unsigned short* wlrfrag = (unsigned short*)alloc(4096 * sizeof(unsigned short));
    float* offlr   = (float*)alloc(16 * sizeof(float));
    float* cvec    = (float*)alloc(256 * sizeof(float));
    float* pbuf    = (float*)alloc(256 * 512 * sizeof(float));
    float* bnscale = (float*)alloc(256 * sizeof(float));
    float* bnshift = (float*)alloc(256 * sizeof(float));

    // CSR build (graph identical for all layers)
    hipMemsetAsync(cnt, 0, NN * sizeof(int), stream);
    k_hist<<<(NE + 255) / 256, 256, 0, stream>>>(dst, cnt);
    k_scan1<<<SCB, 256, 0, stream>>>(cnt, loc, bsum);
    k_scan2<<<1, 256, 0, stream>>>(bsum, boff, rowptr);
    k_scan3<<<SCB, 256, 0, stream>>>(loc, boff, rowptr, cursor);
    k_scatter<<<(NE + 255) / 256, 256, 0, stream>>>(src, dst, cursor, ssrc);
    k_prepw<<<768, 256, 0, stream>>>(W1, W2, W3, Wt);
    k_fold<<<32, 256, 0, stream>>>(Wt, nullptr, nullptr, Wfrag1, nullptr);
    k_foldlr<<<1, 256, 0, stream>>>(Wt, nullptr, nullptr, al1, ar1, wlrfrag, offlr);

    const int GB = (NN + 63) / 64;  // 782
    const int NB = NN / 4;          // 12500

    // ---- layer 1 ----
    k_gemm<<<GB, 256, 0, stream>>>(x, 1, Wfrag1, nullptr, wlrfrag, offlr, feat16, el, er);
    k_agg<<<NB, 256, 0, stream>>>(feat16, el, er, rowptr, ssrc, nullptr, x,
                                  nullptr, nullptr, 0, b1, 1, hbuf, nullptr, 0);
    k_bnstats<<<256, 256, 0, stream>>>(hbuf, pbuf);
    k_bnfinal<<<1, 256, 0, stream>>>(pbuf, g1, be1, bnscale, bnshift);
    k_fold<<<288, 256, 0, stream>>>(Wt + 65536, bnscale, bnshift, Wfrag2, cvec);
    k_foldlr<<<1, 256, 0, stream>>>(Wt + 65536, bnscale, cvec, al2, ar2, wlrfrag, offlr);

    // ---- layer 2 ----
    k_gemm<<<GB, 256, 0, stream>>>(hbuf, 0, Wfrag2, cvec, wlrfrag, offlr, feat16, el, er);
    k_agg<<<NB, 256, 0, stream>>>(feat16, el, er, rowptr, ssrc, hbuf, nullptr,
                                  bnscale, bnshift, 1, b2, 1, hbuf, nullptr, 0);
    k_bnstats<<<256, 256, 0, stream>>>(hbuf, pbuf);
    k_bnfinal<<<1, 256, 0, stream>>>(pbuf, g2, be2, bnscale, bnshift);
    k_fold<<<288, 256, 0, stream>>>(Wt + 131072, bnscale, bnshift, Wfrag2, cvec);
    k_foldlr<<<1, 256, 0, stream>>>(Wt + 131072, bnscale, cvec, al3, ar3, wlrfrag, offlr);

    // ---- layer 3 ----
    k_gemm<<<GB, 256, 0, stream>>>(hbuf, 0, Wfrag2, cvec, wlrfrag, offlr, feat16, el, er);
    k_agg<<<NB, 256, 0, stream>>>(feat16, el, er, rowptr, ssrc, hbuf, nullptr,
                                  bnscale, bnshift, 1, b3, 0, nullptr, out, 1);
}

// Round 9
// 554.299 us; speedup vs baseline: 1.1362x; 1.0412x over previous
//
#include <hip/hip_runtime.h>

constexpr int NN = 50000;     // nodes
constexpr int NE = 800000;    // edges
constexpr float SLOPE_A = 0.2f;   // attention leaky_relu
constexpr float SLOPE_R = 0.01f;  // activation leaky_relu
constexpr int SCB = 196;      // scan blocks: 196*256 = 50176 >= NN

typedef __attribute__((ext_vector_type(8))) short bf16x8;
typedef __attribute__((ext_vector_type(4))) float f32x4;

__device__ __forceinline__ unsigned short f2bf(float f) {
    union { float f; unsigned u; } v; v.f = f;
    unsigned u = v.u;
    unsigned r = u + 0x7fffu + ((u >> 16) & 1u);  // round-to-nearest-even
    return (unsigned short)(r >> 16);
}
__device__ __forceinline__ float bf2f(unsigned short s) {
    union { unsigned u; float f; } v; v.u = ((unsigned)s) << 16;
    return v.f;
}

// ---------------- CSR build ----------------
__global__ void k_hist(const int* __restrict__ dst, int* __restrict__ cnt) {
    int i = blockIdx.x * 256 + threadIdx.x;
    if (i < NE) atomicAdd(&cnt[dst[i]], 1);
}

__global__ void k_scan1(const int* __restrict__ cnt, int* __restrict__ loc,
                        int* __restrict__ bsum) {
    __shared__ int sh[256];
    int t = threadIdx.x;
    int i = blockIdx.x * 256 + t;
    int v = (i < NN) ? cnt[i] : 0;
    sh[t] = v;
    __syncthreads();
    for (int off = 1; off < 256; off <<= 1) {
        int tmp = (t >= off) ? sh[t - off] : 0;
        __syncthreads();
        sh[t] += tmp;
        __syncthreads();
    }
    loc[i] = sh[t] - v;
    if (t == 255) bsum[blockIdx.x] = sh[255];
}

__global__ void k_scan2(const int* __restrict__ bsum, int* __restrict__ boff,
                        int* __restrict__ rowptr) {
    __shared__ int sh[256];
    int t = threadIdx.x;
    int v = (t < SCB) ? bsum[t] : 0;
    sh[t] = v;
    __syncthreads();
    for (int off = 1; off < 256; off <<= 1) {
        int tmp = (t >= off) ? sh[t - off] : 0;
        __syncthreads();
        sh[t] += tmp;
        __syncthreads();
    }
    if (t < SCB) boff[t] = sh[t] - v;
    if (t == 255) rowptr[NN] = sh[255];
}

__global__ void k_scan3(const int* __restrict__ loc, const int* __restrict__ boff,
                        int* __restrict__ rowptr, int* __restrict__ cursor) {
    int i = blockIdx.x * 256 + threadIdx.x;
    if (i < NN) {
        int r = loc[i] + boff[blockIdx.x];
        rowptr[i] = r;
        cursor[i] = r;
    }
}

__global__ void k_scatter(const int* __restrict__ src, const int* __restrict__ dst,
                          int* __restrict__ cursor, int* __restrict__ ssrc) {
    int i = blockIdx.x * 256 + threadIdx.x;
    if (i < NE) {
        int d = dst[i];
        int pos = atomicAdd(&cursor[d], 1);
        ssrc[pos] = src[i];
    }
}

// ---------------- fold: Wfrag + cvec + wl/wr fragment + offlr, all from fp32 W ----
// has_bn=1 grid 296: b<32 Wfrag | 32..287 cvec | 288..295 lr-fold (n=b-288)
// has_bn=0 grid  40: b<32 Wfrag | 32..39 lr-fold (n=b-32)
// Wfrag[((w*8+kc)*4+j)*512 + lane*8 + t] = bf16(sc[k]*W[k][64w+16j+mm]), k=kc*32+q*8+t
// cvec[n] = sum_k sh[k]*W[k][n]
// wlr col n=2h+s: wlrfrag = bf16(sc[k]*raw[k]), raw[k]=sum_d W[k][64h+d]*a[h][d];
// offlr[n] = sum_k sh[k]*raw[k]  (== cvec . a, no cvec dependency)
__global__ void k_fold(const float* __restrict__ W, const float* __restrict__ sc,
                       const float* __restrict__ sh, const float* __restrict__ al,
                       const float* __restrict__ ar, unsigned short* __restrict__ Wfrag,
                       float* __restrict__ cvec, unsigned short* __restrict__ wlrfrag,
                       float* __restrict__ offlr, int has_bn) {
    int b = blockIdx.x;
    if (b < 32) {
        int gid = b * 256 + threadIdx.x;   // < 8192; one thread = 8 shorts
        int lane = gid & 63;
        int frag = gid >> 6;               // 0..127
        int j = frag & 3, kc = (frag >> 2) & 7, w = frag >> 5;
        int mm = lane & 15, q = lane >> 4;
        int n = 64 * w + 16 * j + mm;
        int k0 = kc * 32 + q * 8;
        unsigned short o[8];
#pragma unroll
        for (int t = 0; t < 8; t++) {
            float wv = W[(size_t)(k0 + t) * 256 + n];
            if (sc) wv *= sc[k0 + t];
            o[t] = f2bf(wv);
        }
        *(uint4*)(Wfrag + (size_t)gid * 8) = *(const uint4*)o;
    } else if (has_bn && b < 288) {
        __shared__ float red[256];
        int n = b - 32, k = threadIdx.x;
        red[k] = sh[k] * W[(size_t)k * 256 + n];
        __syncthreads();
        for (int off = 128; off > 0; off >>= 1) {
            if (k < off) red[k] += red[k + off];
            __syncthreads();
        }
        if (k == 0) cvec[n] = red[0];
    } else {
        int n = b - (has_bn ? 288 : 32);   // 0..7
        int h = n >> 1;
        const float* a = (n & 1) ? ar : al;
        int k = threadIdx.x;
        float raw = 0.f;
#pragma unroll 8
        for (int d = 0; d < 64; d++)
            raw += W[(size_t)k * 256 + 64 * h + d] * a[h * 64 + d];
        float val = (sc ? sc[k] : 1.f) * raw;
        int kc = k >> 5, rem = k & 31, q = rem >> 3, t = rem & 7;  // k = kc*32+q*8+t
        wlrfrag[kc * 512 + (q * 16 + n) * 8 + t] = f2bf(val);
        wlrfrag[kc * 512 + (q * 16 + n + 8) * 8 + t] = 0;   // zero the unused col
        __shared__ float red[256];
        red[k] = sh ? sh[k] * raw : 0.f;
        __syncthreads();
        for (int off = 128; off > 0; off >>= 1) {
            if (k < off) red[k] += red[k + off];
            __syncthreads();
        }
        if (k == 0) offlr[n] = red[0];
    }
}

// ---------------- GEMM: feat = A @ Wfrag (+cvec); el/er via extra MFMA --------
// block: 256 thr = 4 waves; tile 64 rows x 256 cols; wave w owns cols [64w,64w+64).
// Wave 0 additionally computes the 8-col el/er matvec with one extra B-frag.
__launch_bounds__(256, 2)
__global__ void k_gemm(const void* __restrict__ Araw, int af32,
                       const unsigned short* __restrict__ Wfrag,
                       const float* __restrict__ cvec,
                       const unsigned short* __restrict__ wlrfrag,
                       const float* __restrict__ offlr,
                       unsigned short* __restrict__ feat16, float* __restrict__ el,
                       float* __restrict__ er) {
    constexpr int AP = 264;  // A lds pitch in bf16 elems (row start 16B-aligned)
    __shared__ __align__(16) unsigned short Alds[64 * AP];
    const int tid = threadIdx.x;
    const int rowbase = blockIdx.x * 64;

    // stage A: 64 rows x 256 bf16
    if (af32) {
        const float* A = (const float*)Araw;
        int r = tid >> 6;
        int c4 = tid & 63;
        for (int it = 0; it < 16; it++) {
            int rr = it * 4 + r;
            int gr = rowbase + rr;
            float4 v = make_float4(0.f, 0.f, 0.f, 0.f);
            if (gr < NN) v = *(const float4*)(A + (size_t)gr * 256 + c4 * 4);
            ushort4 pv;
            pv.x = f2bf(v.x); pv.y = f2bf(v.y); pv.z = f2bf(v.z); pv.w = f2bf(v.w);
            *(ushort4*)(&Alds[rr * AP + c4 * 4]) = pv;
        }
    } else {
        const unsigned short* A = (const unsigned short*)Araw;
        for (int it = 0; it < 8; it++) {
            int idx = it * 256 + tid;
            int rr = idx >> 5;
            int c16 = idx & 31;
            int gr = rowbase + rr;
            uint4 v = make_uint4(0u, 0u, 0u, 0u);
            if (gr < NN) v = *(const uint4*)(A + (size_t)gr * 256 + c16 * 8);
            *(uint4*)(&Alds[rr * AP + c16 * 8]) = v;
        }
    }
    __syncthreads();

    f32x4 acc[4][4];
    for (int i = 0; i < 4; i++)
        for (int j = 0; j < 4; j++)
            acc[i][j] = (f32x4){0.f, 0.f, 0.f, 0.f};
    f32x4 accLR[4];
    for (int i = 0; i < 4; i++) accLR[i] = (f32x4){0.f, 0.f, 0.f, 0.f};

    const int lane = tid & 63, w = tid >> 6;
    const int mm = lane & 15, q = lane >> 4;

    const unsigned short* bbase = Wfrag + ((size_t)w * 8 * 4) * 512 + (size_t)lane * 8;

#pragma unroll
    for (int kc = 0; kc < 8; kc++) {
        bf16x8 a[4], b[4];
        for (int i = 0; i < 4; i++)
            a[i] = *(const bf16x8*)(&Alds[(16 * i + mm) * AP + kc * 32 + q * 8]);
        for (int j = 0; j < 4; j++)
            b[j] = *(const bf16x8*)(bbase + (size_t)(kc * 4 + j) * 512);
        for (int i = 0; i < 4; i++)
            for (int j = 0; j < 4; j++)
                acc[i][j] = __builtin_amdgcn_mfma_f32_16x16x32_bf16(a[i], b[j], acc[i][j], 0, 0, 0);
        if (w == 0) {
            bf16x8 blr = *(const bf16x8*)(wlrfrag + kc * 512 + lane * 8);
            for (int i = 0; i < 4; i++)
                accLR[i] = __builtin_amdgcn_mfma_f32_16x16x32_bf16(a[i], blr, accLR[i], 0, 0, 0);
        }
    }
    __syncthreads();   // all waves done reading Alds before epilogue reuses it

    // ---- folded-BN column offset on feat ----
    if (cvec) {
        float cv[4];
        for (int j = 0; j < 4; j++) cv[j] = cvec[64 * w + 16 * j + mm];
        for (int i = 0; i < 4; i++)
            for (int j = 0; j < 4; j++)
                for (int r = 0; r < 4; r++)
                    acc[i][j][r] += cv[j];
    }

    // ---- el/er write (wave 0, C-layout col=mm -> n=2h+s) ----
    if (w == 0 && mm < 8) {
        float off = offlr[mm];
        int h = mm >> 1;
        float* dstp = (mm & 1) ? er : el;
        for (int i = 0; i < 4; i++)
            for (int r = 0; r < 4; r++) {
                int gr = rowbase + 16 * i + q * 4 + r;
                if (gr < NN) dstp[gr * 4 + h] = accLR[i][r] + off;
            }
    }

    // ---- LDS-bounce feat16 store (C/D layout: col=lane&15, row=(lane>>4)*4+reg) ----
    for (int i = 0; i < 4; i++)
        for (int j = 0; j < 4; j++) {
            int gc = 64 * w + 16 * j + mm;
            for (int r = 0; r < 4; r++) {
                int rr = 16 * i + q * 4 + r;
                Alds[rr * AP + gc] = f2bf(acc[i][j][r]);
            }
        }
    __syncthreads();
    for (int it = 0; it < 8; it++) {
        int idx = it * 256 + tid;
        int rr = idx >> 5;
        int c16 = idx & 31;
        int gr = rowbase + rr;
        if (gr < NN)
            *(uint4*)(feat16 + (size_t)gr * 256 + c16 * 8) = *(const uint4*)(&Alds[rr * AP + c16 * 8]);
    }
}

// ---------------- per-dst softmax + weighted aggregation (bf16 gather) ----------------
// ONE wave per destination node; lane l owns channels [4l,4l+4); head h = l>>4.
// No-max softmax (scores bounded). Predicated unroll-16: avg degree 16 -> most
// nodes complete in a single iteration with 16 gathers in flight.
__launch_bounds__(256)
__global__ void k_agg(const unsigned short* __restrict__ feat16, const float* __restrict__ el,
                      const float* __restrict__ er, const int* __restrict__ rowptr,
                      const int* __restrict__ ssrc,
                      const unsigned short* __restrict__ residh, const float* __restrict__ residf,
                      const float* __restrict__ bnscale, const float* __restrict__ bnshift,
                      int use_bn, const float* __restrict__ bias, int act,
                      unsigned short* __restrict__ outh, float* __restrict__ outf,
                      int final_mean) {
    int n = __builtin_amdgcn_readfirstlane(blockIdx.x * 4 + (threadIdx.x >> 6));
    int l = threadIdx.x & 63;
    int h = l >> 4;
    int beg = rowptr[n], end = rowptr[n + 1];
    float erh = er[n * 4 + h];

    float d = 0.f;
    float4 acc = make_float4(0.f, 0.f, 0.f, 0.f);

    for (int e = beg; e < end; e += 16) {
        int ss[16];
        float cc[16];
        ushort4 ff[16];
#pragma unroll
        for (int j = 0; j < 16; j++) {
            int ee = e + j;
            ss[j] = ssrc[(ee < end) ? ee : beg];
        }
#pragma unroll
        for (int j = 0; j < 16; j++)
            cc[j] = el[ss[j] * 4 + h];
#pragma unroll
        for (int j = 0; j < 16; j++)
            ff[j] = *(const ushort4*)(feat16 + (size_t)ss[j] * 256 + l * 4);
#pragma unroll
        for (int j = 0; j < 16; j++) {
            float sc = cc[j] + erh;
            sc = (sc > 0.f) ? sc : SLOPE_A * sc;
            float wgt = ((e + j) < end) ? __expf(sc) : 0.f;
            d += wgt;
            acc.x += bf2f(ff[j].x) * wgt;
            acc.y += bf2f(ff[j].y) * wgt;
            acc.z += bf2f(ff[j].z) * wgt;
            acc.w += bf2f(ff[j].w) * wgt;
        }
    }

    float invd = 1.f / fmaxf(d, 1e-9f);
    acc.x *= invd; acc.y *= invd; acc.z *= invd; acc.w *= invd;

    // residual (+BN) + bias
    float4 r;
    if (residf) {
        r = *(const float4*)(residf + (size_t)n * 256 + l * 4);
    } else {
        ushort4 rv = *(const ushort4*)(residh + (size_t)n * 256 + l * 4);
        r = make_float4(bf2f(rv.x), bf2f(rv.y), bf2f(rv.z), bf2f(rv.w));
    }
    if (use_bn) {
        float4 sc4 = *(const float4*)(bnscale + l * 4);
        float4 sh4 = *(const float4*)(bnshift + l * 4);
        r.x = r.x * sc4.x + sh4.x;
        r.y = r.y * sc4.y + sh4.y;
        r.z = r.z * sc4.z + sh4.z;
        r.w = r.w * sc4.w + sh4.w;
    }
    float4 bb = *(const float4*)(bias + l * 4);
    acc.x += r.x + bb.x; acc.y += r.y + bb.y;
    acc.z += r.z + bb.z; acc.w += r.w + bb.w;
    if (act) {
        acc.x = (acc.x > 0.f) ? acc.x : SLOPE_R * acc.x;
        acc.y = (acc.y > 0.f) ? acc.y : SLOPE_R * acc.y;
        acc.z = (acc.z > 0.f) ? acc.z : SLOPE_R * acc.z;
        acc.w = (acc.w > 0.f) ? acc.w : SLOPE_R * acc.w;
    }

    if (!final_mean) {
        ushort4 p;
        p.x = f2bf(acc.x); p.y = f2bf(acc.y); p.z = f2bf(acc.z); p.w = f2bf(acc.w);
        *(ushort4*)(outh + (size_t)n * 256 + l * 4) = p;
    } else {
        acc.x += __shfl_xor(acc.x, 16, 64); acc.x += __shfl_xor(acc.x, 32, 64);
        acc.y += __shfl_xor(acc.y, 16, 64); acc.y += __shfl_xor(acc.y, 32, 64);
        acc.z += __shfl_xor(acc.z, 16, 64); acc.z += __shfl_xor(acc.z, 32, 64);
        acc.w += __shfl_xor(acc.w, 16, 64); acc.w += __shfl_xor(acc.w, 32, 64);
        if (l < 16) {
            acc.x *= 0.25f; acc.y *= 0.25f; acc.z *= 0.25f; acc.w *= 0.25f;
            *(float4*)(outf + (size_t)n * 64 + l * 4) = acc;
        }
    }
}

// ---------------- BatchNorm stats: vectorized partials, no atomics ----------------
__global__ void k_bnstats(const unsigned short* __restrict__ hh, float* __restrict__ pbuf) {
    __shared__ float ps[8 * 256];
    __shared__ float ps2[8 * 256];
    int t = threadIdx.x, b = blockIdx.x;
    int r8 = t >> 5, c32 = t & 31;
    int r0 = b * 196, r1 = min(r0 + 196, NN);
    float s[8], s2[8];
#pragma unroll
    for (int e = 0; e < 8; e++) { s[e] = 0.f; s2[e] = 0.f; }
    for (int r = r0 + r8; r < r1; r += 8) {
        uint4 v = *(const uint4*)(hh + (size_t)r * 256 + c32 * 8);
        const unsigned short* pv = (const unsigned short*)&v;
#pragma unroll
        for (int e = 0; e < 8; e++) {
            float f = bf2f(pv[e]);
            s[e] += f; s2[e] += f * f;
        }
    }
#pragma unroll
    for (int e = 0; e < 8; e++) {
        ps[r8 * 256 + c32 * 8 + e] = s[e];
        ps2[r8 * 256 + c32 * 8 + e] = s2[e];
    }
    __syncthreads();
    float ts = 0.f, ts2 = 0.f;
    for (int g = 0; g < 8; g++) { ts += ps[g * 256 + t]; ts2 += ps2[g * 256 + t]; }
    pbuf[b * 512 + t] = ts;
    pbuf[b * 512 + 256 + t] = ts2;
}

__global__ void k_bnfinal(const float* __restrict__ pbuf, const float* __restrict__ g,
                          const float* __restrict__ be, float* __restrict__ scale,
                          float* __restrict__ shift) {
    int t = threadIdx.x;
    float s = 0.f, s2 = 0.f;
    for (int b = 0; b < 256; b++) {
        s += pbuf[b * 512 + t];
        s2 += pbuf[b * 512 + 256 + t];
    }
    float mu = s * (1.f / NN);
    float var = s2 * (1.f / NN) - mu * mu;
    float rs = rsqrtf(var + 1e-5f);
    float sc = rs * g[t];
    scale[t] = sc;
    shift[t] = be[t] - mu * sc;
}

// ---------------- launcher ----------------
extern "C" void kernel_launch(void* const* d_in, const int* in_sizes, int n_in,
                              void* d_out, int out_size, void* d_ws, size_t ws_size,
                              hipStream_t stream) {
    const float* x   = (const float*)d_in[0];
    const int* src   = (const int*)d_in[1];
    const int* dst   = (const int*)d_in[2];
    const float* W1  = (const float*)d_in[3];
    const float* al1 = (const float*)d_in[4];
    const float* ar1 = (const float*)d_in[5];
    const float* b1  = (const float*)d_in[6];
    const float* W2  = (const float*)d_in[7];
    const float* al2 = (const float*)d_in[8];
    const float* ar2 = (const float*)d_in[9];
    const float* b2  = (const float*)d_in[10];
    const float* W3  = (const float*)d_in[11];
    const float* al3 = (const float*)d_in[12];
    const float* ar3 = (const float*)d_in[13];
    const float* b3  = (const float*)d_in[14];
    const float* g1  = (const float*)d_in[15];
    const float* be1 = (const float*)d_in[16];
    const float* g2  = (const float*)d_in[17];
    const float* be2 = (const float*)d_in[18];
    float* out = (float*)d_out;

    char* ws = (char*)d_ws;
    size_t off = 0;
    auto alloc = [&](size_t bytes) {
        void* p = ws + off;
        off += (bytes + 255) & ~(size_t)255;
        return p;
    };
    int* rowptr = (int*)alloc((NN + 1) * sizeof(int));
    int* cursor = (int*)alloc(NN * sizeof(int));
    int* cnt    = (int*)alloc(SCB * 256 * sizeof(int));
    int* loc    = (int*)alloc(SCB * 256 * sizeof(int));
    int* bsum   = (int*)alloc(SCB * sizeof(int));
    int* boff   = (int*)alloc(SCB * sizeof(int));
    int* ssrc   = (int*)alloc(NE * sizeof(int));
    unsigned short* feat16 = (unsigned short*)alloc((size_t)NN * 256 * sizeof(unsigned short));
    unsigned short* hbuf   = (unsigned short*)alloc((size_t)NN * 256 * sizeof(unsigned short));
    float* el   = (float*)alloc((size_t)NN * 4 * sizeof(float));
    float* er   = (float*)alloc((size_t)NN * 4 * sizeof(float));
    unsigned short* Wfrag1  = (unsigned short*)alloc(65536 * sizeof(unsigned short));
    unsigned short* Wfrag2  = (unsigned short*)alloc(65536 * sizeof(unsigned short));
    unsigned short* wlrfrag = (unsigned short*)alloc(4096 * sizeof(unsigned short));
    float* offlr   = (float*)alloc(16 * sizeof(float));
    float* cvec    = (float*)alloc(256 * sizeof(float));
    float* pbuf    = (float*)alloc(256 * 512 * sizeof(float));
    float* bnscale = (float*)alloc(256 * sizeof(float));
    float* bnshift = (float*)alloc(256 * sizeof(float));

    // CSR build (graph identical for all layers)
    hipMemsetAsync(cnt, 0, NN * sizeof(int), stream);
    k_hist<<<(NE + 255) / 256, 256, 0, stream>>>(dst, cnt);
    k_scan1<<<SCB, 256, 0, stream>>>(cnt, loc, bsum);
    k_scan2<<<1, 256, 0, stream>>>(bsum, boff, rowptr);
    k_scan3<<<SCB, 256, 0, stream>>>(loc, boff, rowptr, cursor);
    k_scatter<<<(NE + 255) / 256, 256, 0, stream>>>(src, dst, cursor, ssrc);
    k_fold<<<40, 256, 0, stream>>>(W1, nullptr, nullptr, al1, ar1,
                                   Wfrag1, nullptr, wlrfrag, offlr, 0);

    const int GB = (NN + 63) / 64;  // 782
    const int NB = NN / 4;          // 12500

    // ---- layer 1 ----
    k_gemm<<<GB, 256, 0, stream>>>(x, 1, Wfrag1, nullptr, wlrfrag, offlr, feat16, el, er);
    k_agg<<<NB, 256, 0, stream>>>(feat16, el, er, rowptr, ssrc, nullptr, x,
                                  nullptr, nullptr, 0, b1, 1, hbuf, nullptr, 0);
    k_bnstats<<<256, 256, 0, stream>>>(hbuf, pbuf);
    k_bnfinal<<<1, 256, 0, stream>>>(pbuf, g1, be1, bnscale, bnshift);
    k_fold<<<296, 256, 0, stream>>>(W2, bnscale, bnshift, al2, ar2,
                                    Wfrag2, cvec, wlrfrag, offlr, 1);

    // ---- layer 2 ----
    k_gemm<<<GB, 256, 0, stream>>>(hbuf, 0, Wfrag2, cvec, wlrfrag, offlr, feat16, el, er);
    k_agg<<<NB, 256, 0, stream>>>(feat16, el, er, rowptr, ssrc, hbuf, nullptr,
                                  bnscale, bnshift, 1, b2, 1, hbuf, nullptr, 0);
    k_bnstats<<<256, 256, 0, stream>>>(hbuf, pbuf);
    k_bnfinal<<<1, 256, 0, stream>>>(pbuf, g2, be2, bnscale, bnshift);
    k_fold<<<296, 256, 0, stream>>>(W3, bnscale, bnshift, al3, ar3,
                                    Wfrag2, cvec, wlrfrag, offlr, 1);

    // ---- layer 3 ----
    k_gemm<<<GB, 256, 0, stream>>>(hbuf, 0, Wfrag2, cvec, wlrfrag, offlr, feat16, el, er);
    k_agg<<<NB, 256, 0, stream>>>(feat16, el, er, rowptr, ssrc, hbuf, nullptr,
                                  bnscale, bnshift, 1, b3, 0, nullptr, out, 1);
}